// Round 1
// 2180.178 us; speedup vs baseline: 1.1322x; 1.1322x over previous
//
#include <hip/hip_runtime.h>
#include <hip/hip_bf16.h>
#include <stdint.h>

typedef _Float16 f16;
typedef _Float16 f16x8 __attribute__((ext_vector_type(8)));
typedef float f32x4 __attribute__((ext_vector_type(4)));

#define B_SZ 4096
#define HID  1024
#define LAT  128
#define OBS  64
#define TSEQ 70
#define SPLIT_SCALE 2048.0f        // 2^11
#define SPLIT_INV   (1.0f / 2048.0f)

// ---- fragment-tiled global layout -----------------------------------------
// Matrix [R rows x K cols] stored as chunks of 16 rows x 32 cols; chunk
// (rg, kc) at flat offset ((rg*(K/32))+kc)*512. Within a chunk, element
// (r,k) sits at ((k>>3)&3)*128 + (r&15)*8 + (k&7)  — lane L's 16 B MFMA
// fragment (m=L&15, k=(L>>4)*8..+8) is bytes [L*16, L*16+16).
__device__ __forceinline__ size_t tidx(int row, int k, int K) {
  return (size_t)((row >> 4) * (K >> 5) + (k >> 5)) * 512
       + ((k >> 3) & 3) * 128 + (row & 15) * 8 + (k & 7);
}

// direct global->LDS: PER-LANE global vaddr (caller adds lane*8 f16!),
// wave-uniform LDS base (HW adds lane*16 on the LDS side) [m104/m108].
__device__ __forceinline__ void gl2lds16(const void* g, void* l) {
  __builtin_amdgcn_global_load_lds(
      (const __attribute__((address_space(1))) void*)g,
      (__attribute__((address_space(3))) void*)l, 16, 0, 0);
}

__device__ __forceinline__ float tanh_fast(float x) {
  float e = __expf(2.0f * x);          // inf-safe: x>>0 -> 1, x<<0 -> -1
  return 1.0f - 2.0f / (e + 1.0f);
}

// H = tanh(A @ W^T + bias), double-f16 operands (hi + lo*2^-11 ~ 22-bit):
//   acc0 = A0*W0 ; acc1 = A0*W1' + A1'*W0 ; a = acc0 + acc1*2^-11.
//
// R9 (pipelined): 128x64 tile, BK=32, 3-slot LDS ring (72 KB -> still 2
// blocks/CU) with lead-1 prefetch and COUNTED vmcnt across a raw s_barrier
// (T3+T4): stage(it+1) -> s_waitcnt vmcnt(6) -> s_barrier -> compute(it).
// One barrier per iter. Overwrite safety: a wave staging tile it+1 into slot
// (it+1)%3 has passed barrier(it-1), which implies every wave completed its
// compute(it-2) reads of that slot (program order). Tail peeled with
// vmcnt(0) so the final tile's 6 loads are provably drained (vmcnt(6) at the
// tail would NOT wait for them). Linear block id = bm + 32*bn -> XCD = bm%8:
// H rows stay XCD-local step-to-step (A staging L2-hit).
__global__ __launch_bounds__(256, 2) void rnn_step_split(
    const f16* __restrict__ Ah, const f16* __restrict__ Al,
    const f16* __restrict__ Wh, const f16* __restrict__ Wl,
    const float* __restrict__ bias,
    f16* __restrict__ Hh, f16* __restrict__ Hl, int K)
{
  // slot = {Ah 8x512 | Al 8x512 | Wh 4x512 | Wl 4x512} f16 = 24 KB
  __shared__ __align__(16) f16 ring[3][24 * 512];

  const int lane = threadIdx.x & 63;
  const int wave = threadIdx.x >> 6;
  const int bm = blockIdx.x;      // 32  (M/128)
  const int bn = blockIdx.y;      // 16  (1024/64)
  const int lo8 = lane * 8;       // per-lane 16 B offset within a chunk
  const int kc = K >> 5;          // 32-col chunks per row-group = iter count

  f32x4 acc0[2][4], acc1[2][4];
  const f32x4 z4 = {0.f, 0.f, 0.f, 0.f};
#pragma unroll
  for (int i = 0; i < 2; ++i)
#pragma unroll
    for (int j = 0; j < 4; ++j) { acc0[i][j] = z4; acc1[i][j] = z4; }

  // stage tile 'it' (one 32-wide k-chunk of A hi/lo + W hi/lo): 6 loads/wave
  auto stage = [&](int it, int slot) {
    f16* b = ring[slot];
#pragma unroll
    for (int u = 0; u < 2; ++u) {
      const int rg = wave * 2 + u;
      const size_t ga = (size_t)((bm * 8 + rg) * kc + it) * 512 + lo8;
      gl2lds16(Ah + ga, b + rg * 512);
      gl2lds16(Al + ga, b + (8 + rg) * 512);
    }
    const size_t gw = (size_t)((bn * 4 + wave) * kc + it) * 512 + lo8;
    gl2lds16(Wh + gw, b + (16 + wave) * 512);
    gl2lds16(Wl + gw, b + (20 + wave) * 512);
  };

  // 24 MFMAs per wave per iter (2 i x 4 j x 3 split-terms)
  auto compute = [&](int slot) {
    const f16* b = ring[slot];
    f16x8 vah[2], val[2], vwh[4], vwl[4];
#pragma unroll
    for (int i = 0; i < 2; ++i) {
      vah[i] = *(const f16x8*)&b[(wave * 2 + i) * 512 + lo8];
      val[i] = *(const f16x8*)&b[(8 + wave * 2 + i) * 512 + lo8];
    }
#pragma unroll
    for (int j = 0; j < 4; ++j) {
      vwh[j] = *(const f16x8*)&b[(16 + j) * 512 + lo8];
      vwl[j] = *(const f16x8*)&b[(20 + j) * 512 + lo8];
    }
#pragma unroll
    for (int i = 0; i < 2; ++i)
#pragma unroll
      for (int j = 0; j < 4; ++j) {
        acc0[i][j] = __builtin_amdgcn_mfma_f32_16x16x32_f16(vah[i], vwh[j], acc0[i][j], 0, 0, 0);
        acc1[i][j] = __builtin_amdgcn_mfma_f32_16x16x32_f16(vah[i], vwl[j], acc1[i][j], 0, 0, 0);
        acc1[i][j] = __builtin_amdgcn_mfma_f32_16x16x32_f16(val[i], vwh[j], acc1[i][j], 0, 0, 0);
      }
  };

  stage(0, 0);
  int cur = 0;
  for (int it = 0; it + 1 < kc; ++it) {
    const int nxt = (cur == 2) ? 0 : cur + 1;
    stage(it + 1, nxt);                                  // prefetch next tile
    asm volatile("s_waitcnt vmcnt(6)" ::: "memory");     // my tile-it loads done
    __builtin_amdgcn_s_barrier();                        // everyone's done (no drain)
    compute(cur);
    cur = nxt;
  }
  asm volatile("s_waitcnt vmcnt(0)" ::: "memory");       // tail: drain last tile
  __builtin_amdgcn_s_barrier();
  compute(cur);

  // C/D layout: col=lane&15, row=(lane>>4)*4+reg  [m89-verified]; H stored tiled
  const int rq = lane >> 4;
  const int cl = lane & 15;
#pragma unroll
  for (int j = 0; j < 4; ++j) {
    const int gcol = bn * 64 + j * 16 + cl;
    const float bb = bias[gcol];
#pragma unroll
    for (int i = 0; i < 2; ++i) {
      const int grow = bm * 128 + wave * 32 + i * 16 + rq * 4;
#pragma unroll
      for (int r = 0; r < 4; ++r) {
        const float a = acc0[i][j][r] + acc1[i][j][r] * SPLIT_INV + bb;
        const float t = tanh_fast(a);
        const f16 hi = (f16)t;
        const size_t idx = tidx(grow + r, gcol, HID);
        Hh[idx] = hi;
        Hl[idx] = (f16)((t - (float)hi) * SPLIT_SCALE);  // exact residual, scaled
      }
    }
  }
}

// Y[b,t,:] = H[row,:] @ Who[64,1024]^T + bho over a contiguous ring of hi
// slices. row = s*4096 + b, t = t0 + s. H, Who fragment-tiled; grid = rows/128.
__global__ __launch_bounds__(256, 2) void proj_kernel(
    const f16* __restrict__ H, const f16* __restrict__ Who,
    const float* __restrict__ bho, float* __restrict__ Y, int t0)
{
  __shared__ __align__(16) f16 As[128 * 64];
  __shared__ __align__(16) f16 Bs[64 * 64];
  const int lane = threadIdx.x & 63;
  const int wave = threadIdx.x >> 6;
  const int bm = blockIdx.x;
  const int lo8 = lane * 8;

  f32x4 acc[2][4];
  const f32x4 z4 = {0.f, 0.f, 0.f, 0.f};
#pragma unroll
  for (int i = 0; i < 2; ++i)
#pragma unroll
    for (int j = 0; j < 4; ++j) acc[i][j] = z4;

  for (int kt = 0; kt < HID; kt += 64) {
    const int kch = kt >> 5;
    // A: row-groups bm*8 .. +7, two k-chunks each; 16 chunks, 4/wave
#pragma unroll
    for (int u = 0; u < 4; ++u) {
      const int cidx = wave * 4 + u;
      const int mt = cidx >> 1, s = cidx & 1;
      gl2lds16(H + (size_t)((bm * 8 + mt) * 32 + kch + s) * 512 + lo8, &As[cidx * 512]);
    }
    // Who: row-groups 0..3, two k-chunks; 8 chunks, 2/wave
#pragma unroll
    for (int u = 0; u < 2; ++u) {
      const int cidx = wave * 2 + u;
      const int nt = cidx >> 1, s = cidx & 1;
      gl2lds16(Who + (size_t)(nt * 32 + kch + s) * 512 + lo8, &Bs[cidx * 512]);
    }
    __syncthreads();
#pragma unroll
    for (int s = 0; s < 2; ++s) {
      f16x8 af[2], bfr[4];
#pragma unroll
      for (int i = 0; i < 2; ++i)
        af[i] = *(const f16x8*)&As[(((wave * 2 + i) << 1) | s) * 512 + lo8];
#pragma unroll
      for (int j = 0; j < 4; ++j)
        bfr[j] = *(const f16x8*)&Bs[((j << 1) | s) * 512 + lo8];
#pragma unroll
      for (int i = 0; i < 2; ++i)
#pragma unroll
        for (int j = 0; j < 4; ++j)
          acc[i][j] = __builtin_amdgcn_mfma_f32_16x16x32_f16(af[i], bfr[j], acc[i][j], 0, 0, 0);
    }
    __syncthreads();
  }

  const int rq = lane >> 4;
  const int cl = lane & 15;
#pragma unroll
  for (int j = 0; j < 4; ++j) {
    const int col = j * 16 + cl;
    const float bb = bho[col];
#pragma unroll
    for (int i = 0; i < 2; ++i)
#pragma unroll
      for (int r = 0; r < 4; ++r) {
        const int row = bm * 128 + wave * 32 + i * 16 + rq * 4 + r;
        const int t = t0 + (row >> 12);
        const int b = row & 4095;
        Y[((size_t)b * TSEQ + t) * OBS + col] = acc[i][j][r] + bb;
      }
  }
}

// fp32 [R x K] row-major -> tiled f16 (cast only; for Who)
__global__ void cast_tiled_kernel(const float* __restrict__ x, f16* __restrict__ y,
                                  int K, int n) {
  int i = blockIdx.x * blockDim.x + threadIdx.x;
  if (i < n) y[tidx(i / K, i % K, K)] = (f16)x[i];
}

// fp32 [R x K] row-major -> tiled double-f16 split (for z)
__global__ void split_tiled_kernel(const float* __restrict__ x, f16* __restrict__ hi,
                                   f16* __restrict__ lo, int K, int n) {
  int i = blockIdx.x * blockDim.x + threadIdx.x;
  if (i < n) {
    float v = x[i];
    f16 h = (f16)v;
    size_t o = tidx(i / K, i % K, K);
    hi[o] = h;
    lo[o] = (f16)((v - (float)h) * SPLIT_SCALE);
  }
}

// Weff[n,k] = Whh[n,k] + sum_o Wih[n,o]*Who[o,k]  (fp32, then tiled split)
__global__ void prep_weff(const float* __restrict__ Whh, const float* __restrict__ Wih,
                          const float* __restrict__ Who,
                          f16* __restrict__ Wh, f16* __restrict__ Wl) {
  const int n = blockIdx.x;
  __shared__ float wih_row[OBS];
  if (threadIdx.x < OBS) wih_row[threadIdx.x] = Wih[n * OBS + threadIdx.x];
  __syncthreads();
  for (int k = threadIdx.x; k < HID; k += 256) {
    float s = Whh[(size_t)n * HID + k];
#pragma unroll 8
    for (int o = 0; o < OBS; ++o) s = fmaf(wih_row[o], Who[(size_t)o * HID + k], s);
    const size_t idx = tidx(n, k, HID);
    f16 h = (f16)s;
    Wh[idx] = h;
    Wl[idx] = (f16)((s - (float)h) * SPLIT_SCALE);
  }
}

// W1[n,j] = sum_k Whh[n,k]*Wl2h[k,j]  (fp32, then tiled split)
__global__ void prep_w1(const float* __restrict__ Whh, const float* __restrict__ Wl2h,
                        f16* __restrict__ W1h, f16* __restrict__ W1l) {
  const int n = blockIdx.x, j = threadIdx.x;  // block=128
  float s = 0.f;
  for (int k = 0; k < HID; ++k) s = fmaf(Whh[(size_t)n * HID + k], Wl2h[(size_t)k * LAT + j], s);
  const size_t idx = tidx(n, j, LAT);
  f16 h = (f16)s;
  W1h[idx] = h;
  W1l[idx] = (f16)((s - (float)h) * SPLIT_SCALE);
}

// beff[n] = bih+bhh + Wih@bho ; b1[n] = bih+bhh + Whh@bl2h
__global__ void prep_bias(const float* __restrict__ bih, const float* __restrict__ bhh,
                          const float* __restrict__ bho, const float* __restrict__ Wih,
                          const float* __restrict__ Whh, const float* __restrict__ bl2h,
                          float* __restrict__ beff, float* __restrict__ b1) {
  const int n = blockIdx.x, l = threadIdx.x;  // block=64, one wave
  float s1 = Wih[(size_t)n * OBS + l] * bho[l];
  float s2 = 0.f;
  for (int k = l; k < HID; k += 64) s2 = fmaf(Whh[(size_t)n * HID + k], bl2h[k], s2);
#pragma unroll
  for (int off = 32; off > 0; off >>= 1) {
    s1 += __shfl_down(s1, off);
    s2 += __shfl_down(s2, off);
  }
  if (l == 0) {
    const float base = bih[n] + bhh[n];
    beff[n] = base + s1;
    b1[n]   = base + s2;
  }
}

extern "C" void kernel_launch(void* const* d_in, const int* in_sizes, int n_in,
                              void* d_out, int out_size, void* d_ws, size_t ws_size,
                              hipStream_t stream) {
  (void)in_sizes; (void)n_in; (void)out_size; (void)ws_size;
  const float* z    = (const float*)d_in[0];
  const float* Wl2h = (const float*)d_in[1];
  const float* bl2h = (const float*)d_in[2];
  const float* Wih  = (const float*)d_in[3];
  const float* bih  = (const float*)d_in[4];
  const float* Whh  = (const float*)d_in[5];
  const float* bhh  = (const float*)d_in[6];
  const float* Who  = (const float*)d_in[7];
  const float* bho  = (const float*)d_in[8];
  float* Y = (float*)d_out;

  char* ws = (char*)d_ws;
  size_t off = 0;
  auto take = [&](size_t bytes) {
    char* p = ws + off;
    off = (off + bytes + 255) & ~(size_t)255;
    return p;
  };
  f16*   Weffh = (f16*)take((size_t)HID * HID * 2);
  f16*   Weffl = (f16*)take((size_t)HID * HID * 2);
  f16*   W1h   = (f16*)take((size_t)HID * LAT * 2);
  f16*   W1l   = (f16*)take((size_t)HID * LAT * 2);
  f16*   Whob  = (f16*)take((size_t)OBS * HID * 2);
  f16*   zh    = (f16*)take((size_t)B_SZ * LAT * 2);
  f16*   zl    = (f16*)take((size_t)B_SZ * LAT * 2);
  float* beff  = (float*)take(HID * 4);
  float* b1    = (float*)take(HID * 4);

  const size_t S = (size_t)B_SZ * HID;     // elems per h-slice
  f16* Hlo  = (f16*)take(2 * S * 2);       // lo state, double-buffered
  f16* ring = (f16*)take(8 * S * 2);       // hi state, ring of 8 (~67 MB; ws=280 MB)

  split_tiled_kernel<<<(B_SZ * LAT) / 256, 256, 0, stream>>>(z, zh, zl, LAT, B_SZ * LAT);
  cast_tiled_kernel<<<(OBS * HID) / 256, 256, 0, stream>>>(Who, Whob, HID, OBS * HID);
  prep_weff<<<HID, 256, 0, stream>>>(Whh, Wih, Who, Weffh, Weffl);
  prep_w1<<<HID, LAT, 0, stream>>>(Whh, Wl2h, W1h, W1l);
  prep_bias<<<HID, 64, 0, stream>>>(bih, bhh, bho, Wih, Whh, bl2h, beff, b1);

  dim3 sgrid(B_SZ / 128, HID / 64);   // 32 x 16 = 512 blocks = 2 blocks/CU
  // t = 0: h_1 = tanh(z @ W1^T + b1) -> ring slice 0
  rnn_step_split<<<sgrid, 256, 0, stream>>>(zh, zl, W1h, W1l, b1, ring, Hlo, LAT);
  for (int t = 1; t < TSEQ; ++t) {
    if ((t & 7) == 0)  // ring full: project slices t-8..t-1 before overwriting
      proj_kernel<<<(8 * B_SZ) / 128, 256, 0, stream>>>(ring, Whob, bho, Y, t - 8);
    rnn_step_split<<<sgrid, 256, 0, stream>>>(
        ring + (size_t)((t - 1) & 7) * S, Hlo + (size_t)((t - 1) & 1) * S,
        Weffh, Weffl, beff,
        ring + (size_t)(t & 7) * S, Hlo + (size_t)(t & 1) * S, HID);
  }
  // tail: t = 64..69 live in slices 0..5
  proj_kernel<<<(6 * B_SZ) / 128, 256, 0, stream>>>(ring, Whob, bho, Y, 64);
}